// Round 4
// baseline (362.699 us; speedup 1.0000x reference)
//
#include <hip/hip_runtime.h>
#include <stdint.h>

#define NN 10000
#define NE 160000
#define MPAD 10112   // 79 * 128 = 158 * 64
#define MTILES 79

typedef unsigned short u16;
typedef float f32x4 __attribute__((ext_vector_type(4)));
typedef short short8 __attribute__((ext_vector_type(8)));
typedef __bf16 bf16x8 __attribute__((ext_vector_type(8)));
typedef unsigned short u16x4 __attribute__((ext_vector_type(4)));
typedef unsigned short u16x8 __attribute__((ext_vector_type(8)));

__device__ __forceinline__ float bf2f(u16 u) {
  union { unsigned u; float f; } c; c.u = ((unsigned)u) << 16; return c.f;
}
__device__ __forceinline__ u16 f2bf(float f) {
  union { float f; unsigned u; } c; c.f = f;
  return (u16)((c.u + 0x7FFFu + ((c.u >> 16) & 1u)) >> 16);
}

__device__ __forceinline__ void gld_lds16(void* lds, const void* g) {
  __builtin_amdgcn_global_load_lds(
      (const unsigned int __attribute__((address_space(1)))*)g,
      (unsigned int __attribute__((address_space(3)))*)lds, 16, 0, 0);
}

// ---------------- CSR build ----------------
__global__ __launch_bounds__(256) void deg_count(const int* __restrict__ dst, int* __restrict__ deg) {
  int e = blockIdx.x * 256 + threadIdx.x;
  if (e < NE) atomicAdd(&deg[dst[e]], 1);
}

__global__ __launch_bounds__(256) void scan_off(const int* __restrict__ deg,
                                                int* __restrict__ roff, int* __restrict__ cur) {
  __shared__ int part[256];
  const int t = threadIdx.x;
  const int CH = 40;
  int s = 0;
  for (int i = 0; i < CH; ++i) { int idx = t * CH + i; if (idx < NN) s += deg[idx]; }
  part[t] = s; __syncthreads();
  for (int off = 1; off < 256; off <<= 1) {
    int v = (t >= off) ? part[t - off] : 0;
    __syncthreads(); part[t] += v; __syncthreads();
  }
  int run = (t == 0) ? 0 : part[t - 1];
  for (int i = 0; i < CH; ++i) {
    int idx = t * CH + i;
    if (idx < NN) { roff[idx] = run; cur[idx] = run; run += deg[idx]; }
  }
  if (t == 255) roff[NN] = NE;
}

__global__ __launch_bounds__(256) void fill_csr(const int* __restrict__ src, const int* __restrict__ dst,
                                                int* __restrict__ cur, int* __restrict__ esrc) {
  int e = blockIdx.x * 256 + threadIdx.x;
  if (e < NE) {
    int p = atomicAdd(&cur[dst[e]], 1);
    esrc[p] = src[e];
  }
}

// ---------------- conversions ----------------
__global__ __launch_bounds__(256) void convert_h(const float* __restrict__ h, u16* __restrict__ hbf) {
  const size_t i = (size_t)(blockIdx.x * 256 + threadIdx.x) * 4;
  if (i >= (size_t)MPAD * 960) return;
  u16x4 o;
  if (i < (size_t)NN * 960) {
    float4 v = *(const float4*)(h + i);
    o[0] = f2bf(v.x); o[1] = f2bf(v.y); o[2] = f2bf(v.z); o[3] = f2bf(v.w);
  } else {
    o[0] = 0; o[1] = 0; o[2] = 0; o[3] = 0;
  }
  *(u16x4*)(hbf + i) = o;
}

// weight transposes, K-concat capable: out[c*ldo + koff + r] = bf16(in[r][c])
struct WDesc { const float* in; u16* out; int R, C, Cpad, ldo, koff; };
struct WPack { WDesc d[7]; };

__global__ __launch_bounds__(256) void transpose_all(WPack p) {
  const WDesc w = p.d[blockIdx.z];
  const int cb = blockIdx.x * 32, rb = blockIdx.y * 32;
  if (cb >= w.Cpad || rb >= w.R) return;
  __shared__ float tile[32][33];
  const int tx = threadIdx.x & 31, ty = threadIdx.x >> 5;
  for (int i = ty; i < 32; i += 8) {
    int r = rb + i, c = cb + tx;
    tile[i][tx] = (r < w.R && c < w.C) ? w.in[(size_t)r * w.C + c] : 0.f;
  }
  __syncthreads();
  for (int i = ty; i < 32; i += 8) {
    int c = cb + i, r = rb + tx;
    if (c < w.Cpad && r < w.R) w.out[(size_t)c * w.ldo + w.koff + r] = f2bf(tile[tx][i]);
  }
}

// ---------------- GEMM: Cb = act(([A0|A1]) @ B^T + bias) ----------------
// Measured rounds 0-3: gemm time tracks STAGED BYTES through the per-block
// global_load_lds path at ~10 B/cy/block (invariant to tile size, BK, and
// pipeline depth). B re-staged per M-tile was ~50% of DMA bytes for a
// panel that is L2-resident (0.5-2MB). This version removes B from the
// LDS/DMA path entirely: B fragments are loaded global->register one phase
// ahead (L2 hits, ~64B/row segments), only A (TM x 64) is DMA-staged.
// 3 static LDS buffers (16KB each, compile-time identity; round-2-proven
// no-hidden-drain), one barrier per phase.
// Phase t: vmcnt(NC) [A t + B-frags t landed; stage t+1 in flight] ;
// s_barrier [seals readers of S[(ph+2)%3]] ; ds_read A t ; loadB t+1
// (VMEM loads, BEFORE stage so vmcnt(NC) at next top covers them) ;
// stage A t+2 -> S[(ph+2)%3] ; MFMA with B regs of t.
// Swizzle (8x16B slots/row): phys = logical ^ (row&7), same XOR on global
// source (rule #21). ksplit%64==0 in all uses.
template<int TM, int TN, int MINB>
__global__ __launch_bounds__(256, MINB) void gemm3(
    const u16* __restrict__ A0, int lda0,
    const u16* __restrict__ A1, int lda1, int ksplit,
    const u16* __restrict__ B,
    const float* __restrict__ bias, int nbias,
    u16* __restrict__ Cb, int ldcb,
    int K, int act, int tiles_n) {
  constexpr int NC = TM / 32;        // A-stage gld instrs per lane (8 rows each)
  constexpr int WCOLS = 2;           // TM==128: 2x2 wave grid
  constexpr int WN = TN / WCOLS;     // wave col extent
  constexpr int NJ = WN / 16;        // col frags per wave
  constexpr int MT = MPAD / TM;      // M tiles
  __shared__ __align__(16) u16 S0[TM * 64];
  __shared__ __align__(16) u16 S1[TM * 64];
  __shared__ __align__(16) u16 S2[TM * 64];
  const int tid = threadIdx.x;
  const int wave = tid >> 6, lane = tid & 63;

  // bijective XCD-chunked swizzle over col-fastest linear id (m204)
  const int nwg = tiles_n * MT;
  const int orig = blockIdx.x + blockIdx.y * tiles_n;
  const int q = nwg >> 3, r8 = nwg & 7;
  const int xcd = orig & 7, idx = orig >> 3;
  const int wg = (xcd < r8 ? xcd * (q + 1) : r8 * (q + 1) + (xcd - r8) * q) + idx;
  const int tm = (wg / tiles_n) * TM;
  const int tn = (wg % tiles_n) * TN;

  const int wr = (wave / WCOLS) * 64;
  const int wc = (wave % WCOLS) * WN;
  const int fr = lane & 15, fq = lane >> 4;
  const int sr8 = lane >> 3;         // row within 8-row instr chunk
  const int sslot = lane & 7;        // 16B slot within 128B row
  f32x4 acc[4][NJ] = {};

  auto stage = [&](u16* Sw, int kk) {
#pragma unroll
    for (int c = 0; c < NC; ++c) {
      const int row = c * 32 + wave * 8 + sr8;                // LDS/A row
      const int gs = (sslot ^ (row & 7)) * 8;                 // pre-swizzled k-slot
      const void* g = (kk < ksplit)
          ? (const void*)&A0[(size_t)(tm + row) * lda0 + kk + gs]
          : (const void*)&A1[(size_t)(tm + row) * lda1 + (kk - ksplit) + gs];
      gld_lds16(&Sw[(c * 32 + wave * 8) * 64], g);            // wave-uniform base
    }
  };

  // B fragment loader: global (L2) -> regs. Row = B col, ld = K.
  auto loadB = [&](short8 (&bf)[2 * NJ], int kk) {
#pragma unroll
    for (int j = 0; j < NJ; ++j)
#pragma unroll
      for (int kc = 0; kc < 2; ++kc)
        bf[j * 2 + kc] = *(const short8*)&B[
            (size_t)(tn + wc + j * 16 + fr) * (size_t)K + kk + (((kc << 2) | fq) << 3)];
  };

  const int nsteps = K >> 6;          // BK=64; all K used are multiples of 64
  short8 b0[2 * NJ], b1[2 * NJ], b2[2 * NJ];

  stage(S0, 0);
  loadB(b0, 0);
  __builtin_amdgcn_sched_barrier(0);  // keep b0 loads before stage(S1)
  stage(S1, 64);

  // One phase. bc = B regs for tile t (ready); bn = B regs to fill for t+1.
  auto phase = [&](int t, const u16* Sr, u16* Sw,
                   short8 (&bc)[2 * NJ], short8 (&bn)[2 * NJ]) {
    if (t + 1 < nsteps) {
      asm volatile("s_waitcnt vmcnt(%0)" :: "i"(NC) : "memory");  // A t + B t landed
    } else {
      asm volatile("s_waitcnt vmcnt(0)" ::: "memory");
    }
    __builtin_amdgcn_s_barrier();     // Sw readers (phase t-1) sealed
    __builtin_amdgcn_sched_barrier(0);
    short8 af[4][2];
#pragma unroll
    for (int i = 0; i < 4; ++i) {
      const int r = wr + i * 16 + fr;
#pragma unroll
      for (int kc = 0; kc < 2; ++kc)
        af[i][kc] = *(const short8*)&Sr[r * 64 + ((((kc << 2) | fq) ^ (r & 7)) << 3)];
    }
    if (t + 1 < nsteps) loadB(bn, (t + 1) << 6);
    __builtin_amdgcn_sched_barrier(0);  // B loads issue before stage's DMAs
    if (t + 2 < nsteps) stage(Sw, (t + 2) << 6);
    __builtin_amdgcn_s_setprio(1);
#pragma unroll
    for (int kc = 0; kc < 2; ++kc)
#pragma unroll
      for (int i = 0; i < 4; ++i)
#pragma unroll
        for (int j = 0; j < NJ; ++j)
          acc[i][j] = __builtin_amdgcn_mfma_f32_16x16x32_bf16(
              __builtin_bit_cast(bf16x8, af[i][kc]), __builtin_bit_cast(bf16x8, bc[j * 2 + kc]),
              acc[i][j], 0, 0, 0);
    __builtin_amdgcn_s_setprio(0);
    __builtin_amdgcn_sched_barrier(0);
  };

  for (int base = 0; base < nsteps; base += 3) {
    phase(base, S0, S2, b0, b1);
    if (base + 1 < nsteps) phase(base + 1, S1, S0, b1, b2);
    if (base + 2 < nsteps) phase(base + 2, S2, S1, b2, b0);
  }

  // C/D layout: col=lane&15, row=(lane>>4)*4+reg (m89/m91 verified)
  const int cr = fq * 4, cc = fr;
#pragma unroll
  for (int i = 0; i < 4; ++i)
#pragma unroll
    for (int j = 0; j < NJ; ++j) {
      const int col = tn + wc + j * 16 + cc;
      const float bv = (col < nbias) ? bias[col] : 0.f;
#pragma unroll
      for (int r = 0; r < 4; ++r) {
        const int row = tm + wr + i * 16 + cr + r;
        float v = acc[i][j][r] + bv;
        if (act) v = fmaxf(v, 0.f);
        Cb[(size_t)row * ldcb + col] = f2bf(v);
      }
    }
}

// ---------------- segment max, XCD feature-sliced ----------------
// Feature dim split into 8 slices of CW; slice c pinned to XCD c via
// blockIdx.x & 7. Per-XCD working set MPAD*CW*2B = 2.6MB/1.3MB < 4MB L2.
// relu'd bf16 >= 0: u16 compare == float compare; 0 == empty-segment fill.
template<int CW>
__global__ __launch_bounds__(256) void aggregate_xcd(
    const u16* __restrict__ m, int ldm, const int* __restrict__ roff,
    const int* __restrict__ esrc, u16* __restrict__ neigh, int ldn) {
  constexpr int TPN = CW / 8;          // threads per node
  constexpr int NPB = 256 / TPN;       // nodes per block
  const int chunk = blockIdx.x & 7;
  const int node = (blockIdx.x >> 3) * NPB + threadIdx.x / TPN;
  if (node >= NN) return;
  const int fi = chunk * CW + (threadIdx.x % TPN) * 8;
  const int beg = roff[node], end = roff[node + 1];
  u16x8 a;
#pragma unroll
  for (int i = 0; i < 8; ++i) a[i] = 0;
  for (int e = beg; e < end; ++e) {
    const u16* row = m + (size_t)esrc[e] * ldm;
    u16x8 v = *(const u16x8*)(row + fi);
#pragma unroll
    for (int i = 0; i < 8; ++i) a[i] = (v[i] > a[i]) ? v[i] : a[i];
  }
  *(u16x8*)(neigh + (size_t)node * ldn + fi) = a;
}

// ---------------- layer 2 output: sigmoid(x2 . Ws2 + neigh2 . Wn2 + b2) ----------------
__global__ __launch_bounds__(256) void final_out(
    const u16* __restrict__ x, const u16* __restrict__ neigh,
    const float* __restrict__ ws, const float* __restrict__ wn,
    const float* __restrict__ b, float* __restrict__ out) {
  const int wave = threadIdx.x >> 6, lane = threadIdx.x & 63;
  const int n = blockIdx.x * 4 + wave;
  if (n >= NN) return;
  const int f = lane * 8;
  const u16* xr = x + (size_t)n * 512 + f;
  const u16* nr = neigh + (size_t)n * 512 + f;
  float s = 0.f;
#pragma unroll
  for (int i = 0; i < 8; ++i)
    s += bf2f(xr[i]) * ws[f + i] + bf2f(nr[i]) * wn[f + i];
#pragma unroll
  for (int o = 32; o > 0; o >>= 1) s += __shfl_xor(s, o);
  if (lane == 0) out[n] = 1.f / (1.f + expf(-(s + b[0])));
}

extern "C" void kernel_launch(void* const* d_in, const int* in_sizes, int n_in,
                              void* d_out, int out_size, void* d_ws, size_t ws_size,
                              hipStream_t stream) {
  const float* h   = (const float*)d_in[0];
  const int*   src = (const int*)d_in[1];
  const int*   dst = (const int*)d_in[2];
  const float* Wp0 = (const float*)d_in[3];
  const float* bp0 = (const float*)d_in[4];
  const float* Ws0 = (const float*)d_in[5];
  const float* Wn0 = (const float*)d_in[6];
  const float* b0  = (const float*)d_in[7];
  const float* Wp1 = (const float*)d_in[8];
  const float* bp1 = (const float*)d_in[9];
  const float* Ws1 = (const float*)d_in[10];
  const float* Wn1 = (const float*)d_in[11];
  const float* b1  = (const float*)d_in[12];
  const float* Wp2 = (const float*)d_in[13];
  const float* bp2 = (const float*)d_in[14];
  const float* Ws2 = (const float*)d_in[15];
  const float* Wn2 = (const float*)d_in[16];
  const float* b2  = (const float*)d_in[17];
  float* out = (float*)d_out;

  char* ws = (char*)d_ws;
  size_t off = 0;
  auto alloc = [&](size_t n) { char* p = ws + off; off = (off + n + 255) & ~(size_t)255; return p; };
  u16* hbf   = (u16*)alloc((size_t)MPAD * 960 * 2);
  u16* x1    = (u16*)alloc((size_t)MPAD * 512 * 2);
  u16* x2    = (u16*)alloc((size_t)MPAD * 512 * 2);
  u16* mbuf  = (u16*)alloc((size_t)MPAD * 1024 * 2);
  u16* nbuf  = (u16*)alloc((size_t)MPAD * 1024 * 2);
  u16* WpT0  = (u16*)alloc((size_t)1024 * 960 * 2);   // [1024 cols][K=960]
  u16* Bcat0 = (u16*)alloc((size_t)512 * 1920 * 2);   // [512][Ws0(960) ; Wn0(960)]
  u16* WpT1  = (u16*)alloc((size_t)512 * 512 * 2);
  u16* Bcat1 = (u16*)alloc((size_t)512 * 1024 * 2);   // [512][Ws1(512) ; Wn1(512)]
  u16* WpT2  = (u16*)alloc((size_t)512 * 512 * 2);
  int* deg   = (int*)alloc(NN * 4);
  int* roff  = (int*)alloc((NN + 1) * 4);
  int* curp  = (int*)alloc(NN * 4);
  int* esrc  = (int*)alloc(NE * 4);

  hipMemsetAsync(deg, 0, NN * 4, stream);
  deg_count<<<NE / 256, 256, 0, stream>>>(dst, deg);
  scan_off<<<1, 256, 0, stream>>>(deg, roff, curp);
  fill_csr<<<NE / 256, 256, 0, stream>>>(src, dst, curp, esrc);
  convert_h<<<(MPAD * 960 / 4) / 256, 256, 0, stream>>>(h, hbf);

  WPack wp;
  wp.d[0] = {Wp0, WpT0,  960, 960, 1024,  960,   0};
  wp.d[1] = {Ws0, Bcat0, 960, 512,  512, 1920,   0};
  wp.d[2] = {Wn0, Bcat0, 960, 512,  512, 1920, 960};
  wp.d[3] = {Wp1, WpT1,  512, 512,  512,  512,   0};
  wp.d[4] = {Ws1, Bcat1, 512, 512,  512, 1024,   0};
  wp.d[5] = {Wn1, Bcat1, 512, 512,  512, 1024, 512};
  wp.d[6] = {Wp2, WpT2,  512, 512,  512,  512,   0};
  transpose_all<<<dim3(32, 30, 7), 256, 0, stream>>>(wp);

  // ---- layer 0 (960 -> 512) ----
  // G1: m0 = relu(hbf @ Wp0 + bp0)  [N=1024 padded, 960 real]
  gemm3<128, 128, 2><<<dim3(8, 79), 256, 0, stream>>>(
      hbf, 960, hbf, 960, 960, WpT0, bp0, 960, mbuf, 1024, 960, 1, 8);
  aggregate_xcd<128><<<5000, 256, 0, stream>>>(mbuf, 1024, roff, esrc, nbuf, 1024);
  // G2: x1 = relu([hbf | nbuf] @ [Ws0;Wn0] + b0)  K = 1920
  gemm3<128, 128, 2><<<dim3(4, 79), 256, 0, stream>>>(
      hbf, 960, nbuf, 1024, 960, Bcat0, b0, 512, x1, 512, 1920, 1, 4);

  // ---- layer 1 (512 -> 512) ----
  gemm3<128, 128, 2><<<dim3(4, 79), 256, 0, stream>>>(
      x1, 512, x1, 512, 512, WpT1, bp1, 512, mbuf, 512, 512, 1, 4);
  aggregate_xcd<64><<<2504, 256, 0, stream>>>(mbuf, 512, roff, esrc, nbuf, 512);
  gemm3<128, 128, 2><<<dim3(4, 79), 256, 0, stream>>>(
      x1, 512, nbuf, 512, 512, Bcat1, b1, 512, x2, 512, 1024, 1, 4);

  // ---- layer 2 (512 -> 1) ----
  gemm3<128, 128, 2><<<dim3(4, 79), 256, 0, stream>>>(
      x2, 512, x2, 512, 512, WpT2, bp2, 512, mbuf, 512, 512, 1, 4);
  aggregate_xcd<64><<<2504, 256, 0, stream>>>(mbuf, 512, roff, esrc, nbuf, 512);
  final_out<<<2500, 256, 0, stream>>>(x2, nbuf, Ws2, Wn2, b2, out);
}

// Round 5
// 251.224 us; speedup vs baseline: 1.4437x; 1.4437x over previous
//
#include <hip/hip_runtime.h>
#include <stdint.h>

#define NN 10000
#define NE 160000
#define MPAD 10112   // 79 * 128 = 158 * 64
#define MTILES 79

typedef unsigned short u16;
typedef float f32x4 __attribute__((ext_vector_type(4)));
typedef short short8 __attribute__((ext_vector_type(8)));
typedef __bf16 bf16x8 __attribute__((ext_vector_type(8)));
typedef unsigned short u16x4 __attribute__((ext_vector_type(4)));
typedef unsigned short u16x8 __attribute__((ext_vector_type(8)));

__device__ __forceinline__ float bf2f(u16 u) {
  union { unsigned u; float f; } c; c.u = ((unsigned)u) << 16; return c.f;
}
__device__ __forceinline__ u16 f2bf(float f) {
  union { float f; unsigned u; } c; c.f = f;
  return (u16)((c.u + 0x7FFFu + ((c.u >> 16) & 1u)) >> 16);
}

__device__ __forceinline__ void gld_lds16(void* lds, const void* g) {
  __builtin_amdgcn_global_load_lds(
      (const unsigned int __attribute__((address_space(1)))*)g,
      (unsigned int __attribute__((address_space(3)))*)lds, 16, 0, 0);
}

// ---------------- CSR build ----------------
__global__ __launch_bounds__(256) void deg_count(const int* __restrict__ dst, int* __restrict__ deg) {
  int e = blockIdx.x * 256 + threadIdx.x;
  if (e < NE) atomicAdd(&deg[dst[e]], 1);
}

__global__ __launch_bounds__(256) void scan_off(const int* __restrict__ deg,
                                                int* __restrict__ roff, int* __restrict__ cur) {
  __shared__ int part[256];
  const int t = threadIdx.x;
  const int CH = 40;
  int s = 0;
  for (int i = 0; i < CH; ++i) { int idx = t * CH + i; if (idx < NN) s += deg[idx]; }
  part[t] = s; __syncthreads();
  for (int off = 1; off < 256; off <<= 1) {
    int v = (t >= off) ? part[t - off] : 0;
    __syncthreads(); part[t] += v; __syncthreads();
  }
  int run = (t == 0) ? 0 : part[t - 1];
  for (int i = 0; i < CH; ++i) {
    int idx = t * CH + i;
    if (idx < NN) { roff[idx] = run; cur[idx] = run; run += deg[idx]; }
  }
  if (t == 255) roff[NN] = NE;
}

__global__ __launch_bounds__(256) void fill_csr(const int* __restrict__ src, const int* __restrict__ dst,
                                                int* __restrict__ cur, int* __restrict__ esrc) {
  int e = blockIdx.x * 256 + threadIdx.x;
  if (e < NE) {
    int p = atomicAdd(&cur[dst[e]], 1);
    esrc[p] = src[e];
  }
}

// ---------------- conversions ----------------
__global__ __launch_bounds__(256) void convert_h(const float* __restrict__ h, u16* __restrict__ hbf) {
  const size_t i = (size_t)(blockIdx.x * 256 + threadIdx.x) * 4;
  if (i >= (size_t)MPAD * 960) return;
  u16x4 o;
  if (i < (size_t)NN * 960) {
    float4 v = *(const float4*)(h + i);
    o[0] = f2bf(v.x); o[1] = f2bf(v.y); o[2] = f2bf(v.z); o[3] = f2bf(v.w);
  } else {
    o[0] = 0; o[1] = 0; o[2] = 0; o[3] = 0;
  }
  *(u16x4*)(hbf + i) = o;
}

// weight transposes, K-concat capable: out[c*ldo + koff + r] = bf16(in[r][c])
struct WDesc { const float* in; u16* out; int R, C, Cpad, ldo, koff; };
struct WPack { WDesc d[7]; };

__global__ __launch_bounds__(256) void transpose_all(WPack p) {
  const WDesc w = p.d[blockIdx.z];
  const int cb = blockIdx.x * 32, rb = blockIdx.y * 32;
  if (cb >= w.Cpad || rb >= w.R) return;
  __shared__ float tile[32][33];
  const int tx = threadIdx.x & 31, ty = threadIdx.x >> 5;
  for (int i = ty; i < 32; i += 8) {
    int r = rb + i, c = cb + tx;
    tile[i][tx] = (r < w.R && c < w.C) ? w.in[(size_t)r * w.C + c] : 0.f;
  }
  __syncthreads();
  for (int i = ty; i < 32; i += 8) {
    int c = cb + i, r = rb + tx;
    if (c < w.Cpad && r < w.R) w.out[(size_t)c * w.ldo + w.koff + r] = f2bf(tile[tx][i]);
  }
}

// ---------------- GEMM: Cb = act(([A0|A1]) @ B^T + bias) ----------------
// Model (rounds 0-4): time == one block's serial phase chain; per-phase
// cadence tracks STAGED BYTES / per-block DMA rate (~10 B/cy/block at 4
// waves). Per-CU DMA rate scales with number of DMA-issuing waves (m97:
// 16 waves/CU -> 22 B/cy/CU; our 4-wave blocks at 1.23/CU -> 12 B/cy).
// Round-4 B-from-global gather: 2x REGRESSION (VMEM gather >> DMA). So:
// keep A+B DMA staging, raise DMA concurrency with 8-WAVE BLOCKS (512
// threads), wave grid 2x4 (WN=32, NJ=2), staging split across 8 waves.
// Pipeline (round-3-proven): BK=64, two 32KB buffers, per phase:
// vmcnt(NC) [tile t landed; t+1 in flight] ; s_barrier ; ds_read tile t ;
// lgkmcnt(0) ; s_barrier [all waves' frags in regs] ; stage tile t+2 into
// the same buffer ; MFMA (16/wave).
// Swizzle (8x16B slots per 128B row): phys = logical ^ (row&7), same XOR
// on the pre-swizzled global source (rule #21, involution). 16 rows ->
// 8 slots x2 = 2-way bank aliasing = free (m136). ksplit%64==0 always.
template<int TM, int TN, int MINW>
__global__ __launch_bounds__(512, MINW) void gemm3(
    const u16* __restrict__ A0, int lda0,
    const u16* __restrict__ A1, int lda1, int ksplit,
    const u16* __restrict__ B,
    const float* __restrict__ bias, int nbias,
    u16* __restrict__ Cb, int ldcb,
    int K, int act, int tiles_n) {
  constexpr int TR = TM + TN;        // staged rows per K-tile (256)
  constexpr int NC = TR * 128 / (512 * 16);  // gld instrs per lane per stage (4)
  constexpr int WCOLS = 4;           // 8 waves: 2 rows x 4 cols
  constexpr int WN = TN / WCOLS;     // 32
  constexpr int NJ = WN / 16;        // 2
  constexpr int MT = MPAD / TM;      // M tiles
  __shared__ __align__(16) u16 S0[TR * 64];
  __shared__ __align__(16) u16 S1[TR * 64];
  const int tid = threadIdx.x;
  const int wave = tid >> 6, lane = tid & 63;

  // bijective XCD-chunked swizzle over col-fastest linear id (m204)
  const int nwg = tiles_n * MT;
  const int orig = blockIdx.x + blockIdx.y * tiles_n;
  const int q = nwg >> 3, r8 = nwg & 7;
  const int xcd = orig & 7, idx = orig >> 3;
  const int wg = (xcd < r8 ? xcd * (q + 1) : r8 * (q + 1) + (xcd - r8) * q) + idx;
  const int tm = (wg / tiles_n) * TM;
  const int tn = (wg % tiles_n) * TN;

  const int wr = (wave / WCOLS) * 64;
  const int wc = (wave % WCOLS) * WN;
  const int fr = lane & 15, fq = lane >> 4;
  const int sr8 = lane >> 3;         // row within 8-row wave chunk
  const int sslot = lane & 7;        // 16B slot within 128B row
  f32x4 acc[4][NJ] = {};

  auto stage = [&](u16* Sw, int kk) {
#pragma unroll
    for (int c = 0; c < NC; ++c) {
      const int row = c * 64 + wave * 8 + sr8;                // LDS row
      const int gs = (sslot ^ (row & 7)) * 8;                 // pre-swizzled k-slot
      const void* g;
      if (c < NC * TM / TR) {                                 // A rows (row < TM)
        g = (kk < ksplit)
            ? (const void*)&A0[(size_t)(tm + row) * lda0 + kk + gs]
            : (const void*)&A1[(size_t)(tm + row) * lda1 + (kk - ksplit) + gs];
      } else {                                                // B rows
        g = (const void*)&B[(size_t)(tn + row - TM) * (size_t)K + kk + gs];
      }
      gld_lds16(&Sw[(c * 64 + wave * 8) * 64], g);            // wave-uniform base
    }
  };

  const int nsteps = K >> 6;          // BK=64; all K used are multiples of 64
  stage(S0, 0);
  stage(S1, 64);
  for (int base = 0; base < nsteps; base += 2) {
#pragma unroll
    for (int ph = 0; ph < 2; ++ph) {
      const int t = base + ph;
      if (t >= nsteps) break;
      u16* Sr = (ph == 0) ? S0 : S1;   // holds tile t; also gets tile t+2
      if (t + 1 < nsteps) {
        asm volatile("s_waitcnt vmcnt(%0)" :: "i"(NC) : "memory");  // tile t landed
      } else {
        asm volatile("s_waitcnt vmcnt(0)" ::: "memory");
      }
      __builtin_amdgcn_s_barrier();    // all waves' parts of tile t landed
      __builtin_amdgcn_sched_barrier(0);
      short8 af[4][2], bfr[2][NJ];
#pragma unroll
      for (int i = 0; i < 4; ++i) {
        const int r = wr + i * 16 + fr;
#pragma unroll
        for (int kc = 0; kc < 2; ++kc)
          af[i][kc] = *(const short8*)&Sr[r * 64 + ((((kc << 2) | fq) ^ (r & 7)) << 3)];
      }
#pragma unroll
      for (int j = 0; j < NJ; ++j) {
        const int r = TM + wc + j * 16 + fr;
#pragma unroll
        for (int kc = 0; kc < 2; ++kc)
          bfr[kc][j] = *(const short8*)&Sr[r * 64 + ((((kc << 2) | fq) ^ (r & 7)) << 3)];
      }
      asm volatile("s_waitcnt lgkmcnt(0)" ::: "memory");  // frags in registers
      __builtin_amdgcn_sched_barrier(0);
      __builtin_amdgcn_s_barrier();    // ALL waves done reading Sr -> safe to overwrite
      if (t + 2 < nsteps) stage(Sr, (t + 2) << 6);
      __builtin_amdgcn_s_setprio(1);
#pragma unroll
      for (int kc = 0; kc < 2; ++kc)
#pragma unroll
        for (int i = 0; i < 4; ++i)
#pragma unroll
          for (int j = 0; j < NJ; ++j)
            acc[i][j] = __builtin_amdgcn_mfma_f32_16x16x32_bf16(
                __builtin_bit_cast(bf16x8, af[i][kc]), __builtin_bit_cast(bf16x8, bfr[kc][j]),
                acc[i][j], 0, 0, 0);
      __builtin_amdgcn_s_setprio(0);
      __builtin_amdgcn_sched_barrier(0);
    }
  }

  // C/D layout: col=lane&15, row=(lane>>4)*4+reg (m89/m91 verified)
  const int cr = fq * 4, cc = fr;
#pragma unroll
  for (int i = 0; i < 4; ++i)
#pragma unroll
    for (int j = 0; j < NJ; ++j) {
      const int col = tn + wc + j * 16 + cc;
      const float bv = (col < nbias) ? bias[col] : 0.f;
#pragma unroll
      for (int r = 0; r < 4; ++r) {
        const int row = tm + wr + i * 16 + cr + r;
        float v = acc[i][j][r] + bv;
        if (act) v = fmaxf(v, 0.f);
        Cb[(size_t)row * ldcb + col] = f2bf(v);
      }
    }
}

// ---------------- segment max, XCD feature-sliced ----------------
// Feature dim split into 8 slices of CW; slice c pinned to XCD c via
// blockIdx.x & 7. Per-XCD working set MPAD*CW*2B = 2.6MB/1.3MB < 4MB L2.
// relu'd bf16 >= 0: u16 compare == float compare; 0 == empty-segment fill.
template<int CW>
__global__ __launch_bounds__(256) void aggregate_xcd(
    const u16* __restrict__ m, int ldm, const int* __restrict__ roff,
    const int* __restrict__ esrc, u16* __restrict__ neigh, int ldn) {
  constexpr int TPN = CW / 8;          // threads per node
  constexpr int NPB = 256 / TPN;       // nodes per block
  const int chunk = blockIdx.x & 7;
  const int node = (blockIdx.x >> 3) * NPB + threadIdx.x / TPN;
  if (node >= NN) return;
  const int fi = chunk * CW + (threadIdx.x % TPN) * 8;
  const int beg = roff[node], end = roff[node + 1];
  u16x8 a;
#pragma unroll
  for (int i = 0; i < 8; ++i) a[i] = 0;
  for (int e = beg; e < end; ++e) {
    const u16* row = m + (size_t)esrc[e] * ldm;
    u16x8 v = *(const u16x8*)(row + fi);
#pragma unroll
    for (int i = 0; i < 8; ++i) a[i] = (v[i] > a[i]) ? v[i] : a[i];
  }
  *(u16x8*)(neigh + (size_t)node * ldn + fi) = a;
}

// ---------------- layer 2 output: sigmoid(x2 . Ws2 + neigh2 . Wn2 + b2) ----------------
__global__ __launch_bounds__(256) void final_out(
    const u16* __restrict__ x, const u16* __restrict__ neigh,
    const float* __restrict__ ws, const float* __restrict__ wn,
    const float* __restrict__ b, float* __restrict__ out) {
  const int wave = threadIdx.x >> 6, lane = threadIdx.x & 63;
  const int n = blockIdx.x * 4 + wave;
  if (n >= NN) return;
  const int f = lane * 8;
  const u16* xr = x + (size_t)n * 512 + f;
  const u16* nr = neigh + (size_t)n * 512 + f;
  float s = 0.f;
#pragma unroll
  for (int i = 0; i < 8; ++i)
    s += bf2f(xr[i]) * ws[f + i] + bf2f(nr[i]) * wn[f + i];
#pragma unroll
  for (int o = 32; o > 0; o >>= 1) s += __shfl_xor(s, o);
  if (lane == 0) out[n] = 1.f / (1.f + expf(-(s + b[0])));
}

extern "C" void kernel_launch(void* const* d_in, const int* in_sizes, int n_in,
                              void* d_out, int out_size, void* d_ws, size_t ws_size,
                              hipStream_t stream) {
  const float* h   = (const float*)d_in[0];
  const int*   src = (const int*)d_in[1];
  const int*   dst = (const int*)d_in[2];
  const float* Wp0 = (const float*)d_in[3];
  const float* bp0 = (const float*)d_in[4];
  const float* Ws0 = (const float*)d_in[5];
  const float* Wn0 = (const float*)d_in[6];
  const float* b0  = (const float*)d_in[7];
  const float* Wp1 = (const float*)d_in[8];
  const float* bp1 = (const float*)d_in[9];
  const float* Ws1 = (const float*)d_in[10];
  const float* Wn1 = (const float*)d_in[11];
  const float* b1  = (const float*)d_in[12];
  const float* Wp2 = (const float*)d_in[13];
  const float* bp2 = (const float*)d_in[14];
  const float* Ws2 = (const float*)d_in[15];
  const float* Wn2 = (const float*)d_in[16];
  const float* b2  = (const float*)d_in[17];
  float* out = (float*)d_out;

  char* ws = (char*)d_ws;
  size_t off = 0;
  auto alloc = [&](size_t n) { char* p = ws + off; off = (off + n + 255) & ~(size_t)255; return p; };
  u16* hbf   = (u16*)alloc((size_t)MPAD * 960 * 2);
  u16* x1    = (u16*)alloc((size_t)MPAD * 512 * 2);
  u16* x2    = (u16*)alloc((size_t)MPAD * 512 * 2);
  u16* mbuf  = (u16*)alloc((size_t)MPAD * 1024 * 2);
  u16* nbuf  = (u16*)alloc((size_t)MPAD * 1024 * 2);
  u16* WpT0  = (u16*)alloc((size_t)1024 * 960 * 2);   // [1024 cols][K=960]
  u16* Bcat0 = (u16*)alloc((size_t)512 * 1920 * 2);   // [512][Ws0(960) ; Wn0(960)]
  u16* WpT1  = (u16*)alloc((size_t)512 * 512 * 2);
  u16* Bcat1 = (u16*)alloc((size_t)512 * 1024 * 2);   // [512][Ws1(512) ; Wn1(512)]
  u16* WpT2  = (u16*)alloc((size_t)512 * 512 * 2);
  int* deg   = (int*)alloc(NN * 4);
  int* roff  = (int*)alloc((NN + 1) * 4);
  int* curp  = (int*)alloc(NN * 4);
  int* esrc  = (int*)alloc(NE * 4);

  hipMemsetAsync(deg, 0, NN * 4, stream);
  deg_count<<<NE / 256, 256, 0, stream>>>(dst, deg);
  scan_off<<<1, 256, 0, stream>>>(deg, roff, curp);
  fill_csr<<<NE / 256, 256, 0, stream>>>(src, dst, curp, esrc);
  convert_h<<<(MPAD * 960 / 4) / 256, 256, 0, stream>>>(h, hbf);

  WPack wp;
  wp.d[0] = {Wp0, WpT0,  960, 960, 1024,  960,   0};
  wp.d[1] = {Ws0, Bcat0, 960, 512,  512, 1920,   0};
  wp.d[2] = {Wn0, Bcat0, 960, 512,  512, 1920, 960};
  wp.d[3] = {Wp1, WpT1,  512, 512,  512,  512,   0};
  wp.d[4] = {Ws1, Bcat1, 512, 512,  512, 1024,   0};
  wp.d[5] = {Wn1, Bcat1, 512, 512,  512, 1024, 512};
  wp.d[6] = {Wp2, WpT2,  512, 512,  512,  512,   0};
  transpose_all<<<dim3(32, 30, 7), 256, 0, stream>>>(wp);

  // ---- layer 0 (960 -> 512) ----
  // G1: m0 = relu(hbf @ Wp0 + bp0)  [N=1024 padded, 960 real]
  gemm3<128, 128, 4><<<dim3(8, 79), 512, 0, stream>>>(
      hbf, 960, hbf, 960, 960, WpT0, bp0, 960, mbuf, 1024, 960, 1, 8);
  aggregate_xcd<128><<<5000, 256, 0, stream>>>(mbuf, 1024, roff, esrc, nbuf, 1024);
  // G2: x1 = relu([hbf | nbuf] @ [Ws0;Wn0] + b0)  K = 1920
  gemm3<128, 128, 4><<<dim3(4, 79), 512, 0, stream>>>(
      hbf, 960, nbuf, 1024, 960, Bcat0, b0, 512, x1, 512, 1920, 1, 4);

  // ---- layer 1 (512 -> 512) ----
  gemm3<128, 128, 4><<<dim3(4, 79), 512, 0, stream>>>(
      x1, 512, x1, 512, 512, WpT1, bp1, 512, mbuf, 512, 512, 1, 4);
  aggregate_xcd<64><<<2504, 256, 0, stream>>>(mbuf, 512, roff, esrc, nbuf, 512);
  gemm3<128, 128, 4><<<dim3(4, 79), 512, 0, stream>>>(
      x1, 512, nbuf, 512, 512, Bcat1, b1, 512, x2, 512, 1024, 1, 4);

  // ---- layer 2 (512 -> 1) ----
  gemm3<128, 128, 4><<<dim3(4, 79), 512, 0, stream>>>(
      x2, 512, x2, 512, 512, WpT2, bp2, 512, mbuf, 512, 512, 1, 4);
  aggregate_xcd<64><<<2504, 256, 0, stream>>>(mbuf, 512, roff, esrc, nbuf, 512);
  final_out<<<2500, 256, 0, stream>>>(x2, nbuf, Ws2, Wn2, b2, out);
}